// Round 10
// baseline (250.314 us; speedup 1.0000x reference)
//
#include <hip/hip_runtime.h>

// Quantum circuit sim: 12 wires, DIM=4096, 3 layers, batch=512, fp32.
// R10 = R9 (zero-barrier single-wave blocks) + explicit VGPR-budget pin.
// R9's counters showed WRITE_SIZE ~100MB = scratch spills: the allocator
// used a 4-waves/EU default budget (~128 VGPRs) and spilled amp[64]
// (128 VGPRs). amdgpu_waves_per_eu(1,1) pins the budget at 512 VGPRs/wave.
//
// Structure (validated correct by R9's absmax pass):
//  - 64-thread blocks = ONE wave -> wave-synchronous LDS, no s_barrier ever.
//  - lane L holds amp[k] = psi[(k<<6)|L], k=0..63 (128 VGPRs).
//  - wires 0-5 = k-bits in-register (v_pk asm core); one LDS transpose ->
//    wires 6-11 in k; CNOT Gray perm folded into the layer-boundary gather;
//    final perm folded into measurement weights via inverse-Gray.
//  - storage S(i) = 65*i[5:0] + i[11:6] (float2): every phase = base VGPR +
//    compile-time immediates; worst conflict 4-way (measured trivial in R9).

namespace {

typedef float v2f __attribute__((ext_vector_type(2)));

constexpr int N_WIRES = 12;
constexpr int DIM     = 1 << N_WIRES;   // 4096
constexpr int PER     = 64;             // amps per lane
constexpr int NG      = 36;

// invGray6: prefix-xor from MSB (6-bit)
__host__ __device__ constexpr int ig6(int x) {
    int y = x; y ^= y >> 1; y ^= y >> 2; y ^= y >> 4; return y & 63;
}

// ---- Packed complex helpers. v2f = (re, im) in a VGPR pair.
// d = u * p:
//   inst1: d.lo = p.re*u.re          d.hi = p.im*u.re
//   inst2: d.lo += p.im*(-u.im)      d.hi += p.re*u.im
__device__ __forceinline__ v2f cmul(v2f u, v2f p) {
    v2f d;
    asm("v_pk_mul_f32 %0, %1, %2 op_sel_hi:[1,0]"
        : "=v"(d) : "v"(p), "v"(u));
    asm("v_pk_fma_f32 %0, %1, %2, %0 op_sel:[1,1,0] op_sel_hi:[0,1,1] neg_lo:[0,1,0]"
        : "+v"(d) : "v"(p), "v"(u));
    return d;
}
// d += u * p
__device__ __forceinline__ void cfma(v2f& d, v2f u, v2f p) {
    asm("v_pk_fma_f32 %0, %1, %2, %0 op_sel_hi:[1,0,1]"
        : "+v"(d) : "v"(p), "v"(u));
    asm("v_pk_fma_f32 %0, %1, %2, %0 op_sel:[1,1,0] op_sel_hi:[0,1,1] neg_lo:[0,1,0]"
        : "+v"(d) : "v"(p), "v"(u));
}

__global__ __launch_bounds__(64)
__attribute__((amdgpu_waves_per_eu(1, 1)))
void qcirc_kernel(const float* __restrict__ state,
                  const float* __restrict__ weights,
                  const float* __restrict__ head_w,
                  const float* __restrict__ head_b,
                  float* __restrict__ out)
{
    __shared__ __align__(16) v2f buf[65 * 64];      // S(i)=65*lo+hi, 33.3 KB
    __shared__ __align__(16) v2f Um[NG][4];

    const int L = threadIdx.x;                      // lane, 6 bits
    const int b = blockIdx.x;

    // ---- 36 gate matrices (lanes 0-35). U = RZ(c)RY(b)RX(a); SU(2):
    // U = [[u00, -conj(u10)], [u10, conj(u00)]].
    if (L < NG) {
        const float* wp = weights + L * 3;
        float ha = 0.5f * wp[0], hb = 0.5f * wp[1], hc = 0.5f * wp[2];
        float ca = cosf(ha), sa = sinf(ha);
        float cb = cosf(hb), sb = sinf(hb);
        float ecr = cosf(hc), eci = -sinf(hc);      // e^{-i c/2}
        float t0 = cb * ca, t1 = sb * sa, t2 = sb * ca, t3 = cb * sa;
        float u00r =  ecr * t0 - eci * t1;
        float u00i =  ecr * t1 + eci * t0;
        float u10r =  ecr * t2 - eci * t3;
        float u10i = -ecr * t3 - eci * t2;
        Um[L][0] = (v2f){ u00r,  u00i};             // u00
        Um[L][1] = (v2f){-u10r,  u10i};             // u01 = -conj(u10)
        Um[L][2] = (v2f){ u10r,  u10i};             // u10
        Um[L][3] = (v2f){ u00r, -u00i};             // u11 = conj(u00)
    }

    // ---- Initial load, phase-1 layout: amp[k] = state[(k<<6)|L] (coalesced).
    v2f amp[PER];
    {
        const float* sp = state + (size_t)b * DIM + L;
        #pragma unroll
        for (int k = 0; k < PER; ++k)
            amp[k] = (v2f){sp[k << 6], 0.f};
    }

    // ---- Gather bases (CNOT Gray perm), runtime parts.
    const int gL  = L ^ (L >> 1);                   // gray6(L)
    const int gb0 = 65 * gL;                        // k even
    const int gb1 = 65 * (gL ^ 32);                 // k odd (j bit5 ^= k&1)

    // Um visible to all lanes (single wave: waitcnt suffices, no barrier)
    asm volatile("s_waitcnt lgkmcnt(0)" ::: "memory");

    int gi = 0;                                     // gate index 0..35
    #pragma unroll 1
    for (int l = 0; l < 3; ++l) {
        #pragma unroll 1
        for (int rep = 0; rep < 2; ++rep) {
            // 6 gates on k-bits 5..0 (rep0: wires 0-5; rep1: wires 6-11)
            #pragma unroll
            for (int gg = 0; gg < 6; ++gg) {
                const v2f u00 = Um[gi + gg][0];
                const v2f u01 = Um[gi + gg][1];
                const v2f u10 = Um[gi + gg][2];
                const v2f u11 = Um[gi + gg][3];
                const int st = 32 >> gg;
                #pragma unroll
                for (int k0 = 0; k0 < PER; ++k0) {
                    if (k0 & st) continue;          // static under full unroll
                    const int k1 = k0 | st;
                    const v2f p = amp[k0], q = amp[k1];
                    v2f np = cmul(u00, p); cfma(np, u01, q);
                    v2f nq = cmul(u10, p); cfma(nq, u11, q);
                    amp[k0] = np;
                    amp[k1] = nq;
                }
            }
            gi += 6;
            if (rep == 0) {
                // P1-write: element (k<<6)|L at S = 65L + k (imm 8k bytes)
                #pragma unroll
                for (int k = 0; k < PER; ++k) buf[65 * L + k] = amp[k];
                asm volatile("s_waitcnt lgkmcnt(0)" ::: "memory");
                // transpose-read: element (L<<6)|k at S = 65k + L
                #pragma unroll
                for (int k = 0; k < PER; ++k) amp[k] = buf[L + 65 * k];
            }
        }
        if (l < 2) {
            // P2-write: element (L<<6)|k at S = 65k + L — exactly the slots
            // THIS lane read in the transpose (per-lane RAW only, safe).
            #pragma unroll
            for (int k = 0; k < PER; ++k) buf[L + 65 * k] = amp[k];
            asm volatile("s_waitcnt lgkmcnt(0)" ::: "memory");
            // CNOT gather into phase-1: amp[k] = psi[gray12((k<<6)|L)],
            // addr = 65*(gL ^ ((k&1)<<5)) + gray6(k)
            #pragma unroll
            for (int k = 0; k < PER; ++k) {
                const int gk = (k ^ (k >> 1)) & 63; // static
                amp[k] = buf[((k & 1) ? gb1 : gb0) + gk];
            }
            asm volatile("s_waitcnt lgkmcnt(0)" ::: "memory");
        }
    }

    // ---- Measurement. Regs: pre-final-CNOT state at j = (L<<6)|k.
    // Logical m = invGray12(j): m[11:6] = invGray6(L),
    // m[5:0] = invGray6(k) ^ (parity(L)*63).
    // acc_L = chi_L * P + sign(L) * Q;  P = sum p_k;
    // Q = sum_w hw[6+w] * T_w, T_w accumulated with static per-k signs.
    float hw[N_WIRES];
    #pragma unroll
    for (int w = 0; w < N_WIRES; ++w) hw[w] = head_w[w];

    float P = 0.f, T0 = 0.f, T1 = 0.f, T2 = 0.f, T3 = 0.f, T4 = 0.f, T5 = 0.f;
    #pragma unroll
    for (int k = 0; k < PER; ++k) {
        const float p = amp[k].x * amp[k].x + amp[k].y * amp[k].y;
        P += p;
        const int mg = ig6(k);                      // static
        if (mg & 32) T0 -= p; else T0 += p;         // wire 6  <- m bit 5
        if (mg & 16) T1 -= p; else T1 += p;         // wire 7
        if (mg &  8) T2 -= p; else T2 += p;         // wire 8
        if (mg &  4) T3 -= p; else T3 += p;         // wire 9
        if (mg &  2) T4 -= p; else T4 += p;         // wire 10
        if (mg &  1) T5 -= p; else T5 += p;         // wire 11
    }
    float Q = hw[6] * T0 + hw[7] * T1 + hw[8] * T2
            + hw[9] * T3 + hw[10] * T4 + hw[11] * T5;

    int iL = L; iL ^= iL >> 1; iL ^= iL >> 2; iL ^= iL >> 4;  // invGray6(L)
    float chi = 0.f;
    #pragma unroll
    for (int w = 0; w < 6; ++w)
        chi += ((iL >> (5 - w)) & 1) ? -hw[w] : hw[w];

    float acc = chi * P + ((__popc(L) & 1) ? -Q : Q);

    #pragma unroll
    for (int off = 32; off > 0; off >>= 1)
        acc += __shfl_down(acc, off, 64);
    if (L == 0) out[b] = acc + head_b[0];
}

} // namespace

extern "C" void kernel_launch(void* const* d_in, const int* in_sizes, int n_in,
                              void* d_out, int out_size, void* d_ws, size_t ws_size,
                              hipStream_t stream)
{
    const float* state   = (const float*)d_in[0];  // (B, 4096) fp32
    const float* weights = (const float*)d_in[1];  // (3, 12, 3) fp32
    const float* head_w  = (const float*)d_in[2];  // (1, 12) fp32
    const float* head_b  = (const float*)d_in[3];  // (1,) fp32
    float* out = (float*)d_out;                    // (B,) fp32

    const int batch = in_sizes[0] / DIM;           // 512
    qcirc_kernel<<<batch, 64, 0, stream>>>(state, weights, head_w, head_b, out);
}

// Round 11
// 91.411 us; speedup vs baseline: 2.7383x; 2.7383x over previous
//
#include <hip/hip_runtime.h>

// Quantum circuit sim: 12 wires, DIM=4096, 3 layers, batch=512, fp32.
// R11: zero-barrier single-wave blocks WITHOUT the 64-deep register file.
// R9/R10 failed because LLVM refuses to promote a 512B amp[64] alloca ->
// scratch spills (~100MB WRITE_SIZE). Here the state stays in LDS and
// streams through 16-amp register chunks (16-elem v2f arrays promoted fine
// in R2-R8). One wave per block -> wave-synchronous LDS: only s_waitcnt
// lgkmcnt(0) at stage boundaries, zero s_barrier.
//
// Storage S(i) = 65*(i>>6) + (i&63) (v2f units), double-buffered per layer
// (gather must not overwrite its own source). Stages per layer:
//   A: wires 0-3  = i bits 11..8 in k;  i = (k<<8)|(L<<2)|c
//   B: wires 4-7  = i bits 7..4  in k;  i = ((L>>2)<<8)|(k<<4)|(c<<2)|(L&3)
//   C: wires 8-11 = i bits 3..0  in k;  i = (c<<10)|(L<<4)|k
// All stages verified bank-conflict structural-minimum (4 lanes/bank-pair
// for b64), all k-offsets compile-time immediates.
// CNOT chain = Gray map perm(i)=i^(i>>1), folded into the layer-boundary
// gather (replaces stage-A read); final perm folded into measurement signs.

namespace {

typedef float v2f __attribute__((ext_vector_type(2)));

constexpr int DIM  = 4096;
constexpr int NG   = 36;
constexpr int BUFV = 65 * 64;          // 4160 v2f per buffer

// d = u * p (complex):
__device__ __forceinline__ v2f cmul(v2f u, v2f p) {
    v2f d;
    asm("v_pk_mul_f32 %0, %1, %2 op_sel_hi:[1,0]"
        : "=v"(d) : "v"(p), "v"(u));
    asm("v_pk_fma_f32 %0, %1, %2, %0 op_sel:[1,1,0] op_sel_hi:[0,1,1] neg_lo:[0,1,0]"
        : "+v"(d) : "v"(p), "v"(u));
    return d;
}
// d += u * p
__device__ __forceinline__ void cfma(v2f& d, v2f u, v2f p) {
    asm("v_pk_fma_f32 %0, %1, %2, %0 op_sel_hi:[1,0,1]"
        : "+v"(d) : "v"(p), "v"(u));
    asm("v_pk_fma_f32 %0, %1, %2, %0 op_sel:[1,1,0] op_sel_hi:[0,1,1] neg_lo:[0,1,0]"
        : "+v"(d) : "v"(p), "v"(u));
}

// 4 gates on k-bits 3..0 (gate gg pairs k-bit 3-gg). ur = 16 v2f in regs.
__device__ __forceinline__ void gates4(v2f amp[16], const v2f ur[16])
{
    #pragma unroll
    for (int gg = 0; gg < 4; ++gg) {
        const v2f u00 = ur[gg * 4 + 0];
        const v2f u01 = ur[gg * 4 + 1];
        const v2f u10 = ur[gg * 4 + 2];
        const v2f u11 = ur[gg * 4 + 3];
        const int st = 8 >> gg;
        #pragma unroll
        for (int k0 = 0; k0 < 16; ++k0) {
            if (k0 & st) continue;             // static under full unroll
            const int k1 = k0 | st;
            const v2f p = amp[k0], q = amp[k1];
            v2f np = cmul(u00, p); cfma(np, u01, q);
            v2f nq = cmul(u10, p); cfma(nq, u11, q);
            amp[k0] = np;
            amp[k1] = nq;
        }
    }
}

__global__ __launch_bounds__(64)
void qcirc_kernel(const float* __restrict__ state,
                  const float* __restrict__ weights,
                  const float* __restrict__ head_w,
                  const float* __restrict__ head_b,
                  float* __restrict__ out)
{
    __shared__ __align__(16) v2f buf[2 * BUFV];     // 66.6 KB
    __shared__ __align__(16) v2f Um[NG][4];

    const int L = threadIdx.x;                      // lane, 6 bits
    const int b = blockIdx.x;

    // ---- 36 gate matrices (lanes 0-35). U = RZ(c)RY(b)RX(a); SU(2):
    // U = [[u00, -conj(u10)], [u10, conj(u00)]].
    if (L < NG) {
        const float* wp = weights + L * 3;
        float ha = 0.5f * wp[0], hb = 0.5f * wp[1], hc = 0.5f * wp[2];
        float ca = cosf(ha), sa = sinf(ha);
        float cb = cosf(hb), sb = sinf(hb);
        float ecr = cosf(hc), eci = -sinf(hc);      // e^{-i c/2}
        float t0 = cb * ca, t1 = sb * sa, t2 = sb * ca, t3 = cb * sa;
        float u00r =  ecr * t0 - eci * t1;
        float u00i =  ecr * t1 + eci * t0;
        float u10r =  ecr * t2 - eci * t3;
        float u10i = -ecr * t3 - eci * t2;
        Um[L][0] = (v2f){ u00r,  u00i};             // u00
        Um[L][1] = (v2f){-u10r,  u10i};             // u01 = -conj(u10)
        Um[L][2] = (v2f){ u10r,  u10i};             // u10
        Um[L][3] = (v2f){ u00r, -u00i};             // u11 = conj(u00)
    }

    // ---- per-lane bases (v2f units)
    const int bA = 65 * (L >> 4) + 4 * (L & 15);    // stage A: + c + 260k
    const int bB = 260 * (L >> 2) + (L & 3);        // stage B: + 4c + offB[k]
    const int bC = 65 * (L >> 2) + 16 * (L & 3);    // stage C: + 1040c + k
    // gather: S(gray12((k<<8)|(L<<2)|c)) = q_{k&1} + wc(c) + 260*gray4(k)
    const int glo = (L ^ (L >> 1)) & 15;
    const int L5 = (L >> 5) & 1, L4 = (L >> 4) & 1, L0 = L & 1;
    const int q0 = 65 * ((L5 << 1) | (L5 ^ L4)) + (glo << 2);        // k even
    const int q1 = 65 * (((1 ^ L5) << 1) | (L5 ^ L4)) + (glo << 2);  // k odd

    asm volatile("s_waitcnt lgkmcnt(0)" ::: "memory");   // Um visible (1 wave)

    v2f amp[16];

    // ---- Layer 0 stage A: global load + wires 0-3 -> buf0
    {
        v2f ur[16];
        #pragma unroll
        for (int j = 0; j < 16; ++j) ur[j] = Um[j >> 2][j & 3];   // gates 0-3
        const float* gp = state + (size_t)b * DIM + (L << 2);
        #pragma unroll 1
        for (int c = 0; c < 4; ++c) {
            #pragma unroll
            for (int k = 0; k < 16; ++k)
                amp[k] = (v2f){gp[(k << 8) + c], 0.f};
            gates4(amp, ur);
            const int a0 = bA + c;
            #pragma unroll
            for (int k = 0; k < 16; ++k) buf[a0 + 260 * k] = amp[k];
        }
    }
    asm volatile("s_waitcnt lgkmcnt(0)" ::: "memory");

    #pragma unroll 1
    for (int l = 0; l < 3; ++l) {
        const int q = (l & 1) * BUFV;               // this layer's buffer
        const int gbase = l * 12;

        // ---- stage B: wires 4-7 (read+write buf q, same addrs)
        {
            v2f ur[16];
            const v2f* up = &Um[gbase + 4][0];
            #pragma unroll
            for (int j = 0; j < 16; ++j) ur[j] = up[j];
            #pragma unroll 1
            for (int c = 0; c < 4; ++c) {
                const int a0 = q + bB + 4 * c;
                #pragma unroll
                for (int k = 0; k < 16; ++k)
                    amp[k] = buf[a0 + 65 * (k >> 2) + 16 * (k & 3)];
                gates4(amp, ur);
                #pragma unroll
                for (int k = 0; k < 16; ++k)
                    buf[a0 + 65 * (k >> 2) + 16 * (k & 3)] = amp[k];
            }
        }
        asm volatile("s_waitcnt lgkmcnt(0)" ::: "memory");

        // ---- stage C: wires 8-11 (read+write buf q, same addrs)
        {
            v2f ur[16];
            const v2f* up = &Um[gbase + 8][0];
            #pragma unroll
            for (int j = 0; j < 16; ++j) ur[j] = up[j];
            #pragma unroll 1
            for (int c = 0; c < 4; ++c) {
                const int a0 = q + bC + 1040 * c;
                #pragma unroll
                for (int k = 0; k < 16; ++k) amp[k] = buf[a0 + k];
                gates4(amp, ur);
                #pragma unroll
                for (int k = 0; k < 16; ++k) buf[a0 + k] = amp[k];
            }
        }
        asm volatile("s_waitcnt lgkmcnt(0)" ::: "memory");

        // ---- next layer's stage A: CNOT-Gray gather from buf q,
        //      wires 0-3 of layer l+1, write buf 1-q  (no WAR: other buffer)
        if (l < 2) {
            v2f ur[16];
            const v2f* up = &Um[gbase + 12][0];
            #pragma unroll
            for (int j = 0; j < 16; ++j) ur[j] = up[j];
            const int qn = BUFV - q;                // the other buffer
            #pragma unroll 1
            for (int c = 0; c < 4; ++c) {
                const int c1 = (c >> 1) & 1, c0 = c & 1;
                const int wc = ((L0 ^ c1) << 1) | (c1 ^ c0);
                const int g0 = q + q0 + wc, g1 = q + q1 + wc;
                #pragma unroll
                for (int k = 0; k < 16; ++k) {
                    const int g4 = k ^ (k >> 1);    // gray4(k), static
                    amp[k] = buf[((k & 1) ? g1 : g0) + 260 * g4];
                }
                gates4(amp, ur);
                const int a0 = qn + bA + c;
                #pragma unroll
                for (int k = 0; k < 16; ++k) buf[a0 + 260 * k] = amp[k];
            }
            asm volatile("s_waitcnt lgkmcnt(0)" ::: "memory");
        }
    }

    // ---- Measurement. Final state in stage-C layout, buf0 (layer 2: q=0),
    // pre-final-CNOT at j = (c<<10)|(L<<4)|k. Logical m = invGray12(j):
    //   m11 = c1, m10 = c1^c0, m[9:4] = invGray6(L) ^ (pc?0x3F:0),
    //   m[3:0] = invGray4(k) ^ ((pc^parL)?0xF:0),  pc = c1^c0.
    // Fold: acc = hw0*Z0 + (hw1 + A_L)*Z1 + (-1)^parL * sum_w hw[8+w]*T_w,
    //   Z0 = sum (-1)^{c1} p,  Z1 = sum (-1)^{pc} p,
    //   T_w = sum (-1)^{ig4(k) bit (3-w) ^ pc} p,  A_L = sum_{w=2..7} +-hw[w].
    float hw[12];
    #pragma unroll
    for (int w = 0; w < 12; ++w) hw[w] = head_w[w];

    float Z0 = 0.f, Z1 = 0.f, T8 = 0.f, T9 = 0.f, T10 = 0.f, T11 = 0.f;
    #pragma unroll
    for (int c = 0; c < 4; ++c) {
        const int a0 = bC + 1040 * c;
        const int pc = (c ^ (c >> 1)) & 1;          // c1^c0, static
        #pragma unroll
        for (int k = 0; k < 16; ++k) {
            const v2f a = buf[a0 + k];
            const float p = a.x * a.x + a.y * a.y;
            const int ig4 = (k ^ (k >> 1) ^ (k >> 2) ^ (k >> 3)) & 15;
            Z0 += ((c >> 1) & 1) ? -p : p;
            Z1 += pc ? -p : p;
            T8  += ((((ig4 >> 3) & 1) ^ pc) ? -p : p);
            T9  += ((((ig4 >> 2) & 1) ^ pc) ? -p : p);
            T10 += ((((ig4 >> 1) & 1) ^ pc) ? -p : p);
            T11 += ((( ig4       & 1) ^ pc) ? -p : p);
        }
    }

    int iL = L ^ (L >> 1); iL ^= iL >> 2; iL ^= iL >> 4;   // invGray6(L)
    float A_L = 0.f;
    #pragma unroll
    for (int w = 2; w < 8; ++w)
        A_L += ((iL >> (7 - w)) & 1) ? -hw[w] : hw[w];
    const float tpart = hw[8] * T8 + hw[9] * T9 + hw[10] * T10 + hw[11] * T11;
    float acc = hw[0] * Z0 + (hw[1] + A_L) * Z1 + ((iL & 1) ? -tpart : tpart);

    #pragma unroll
    for (int off = 32; off > 0; off >>= 1)
        acc += __shfl_down(acc, off, 64);
    if (L == 0) out[b] = acc + head_b[0];
}

} // namespace

extern "C" void kernel_launch(void* const* d_in, const int* in_sizes, int n_in,
                              void* d_out, int out_size, void* d_ws, size_t ws_size,
                              hipStream_t stream)
{
    const float* state   = (const float*)d_in[0];  // (B, 4096) fp32
    const float* weights = (const float*)d_in[1];  // (3, 12, 3) fp32
    const float* head_w  = (const float*)d_in[2];  // (1, 12) fp32
    const float* head_b  = (const float*)d_in[3];  // (1,) fp32
    float* out = (float*)d_out;                    // (B,) fp32

    const int batch = in_sizes[0] / DIM;           // 512
    qcirc_kernel<<<batch, 64, 0, stream>>>(state, weights, head_w, head_b, out);
}

// Round 12
// 83.186 us; speedup vs baseline: 3.0091x; 1.0989x over previous
//
#include <hip/hip_runtime.h>

// Quantum circuit sim: 12 wires, DIM=4096, 3 layers, batch=512, fp32.
// R12: R7's occupancy (256-thr blocks, 2 blocks/CU, 2 waves/SIMD) with the
// barrier count cut 11 -> 5. Fixed A-layout i=(k<<8)|t the whole kernel:
//   wires 0-3  = k bits      -> in-register gates (v_pk asm core)
//   wires 6-11 = lane bits   -> __shfl_xor gates (wave-local, NO barrier)
//   wires 4-5  = wave bits   -> fused 4x4 gate (U4 x U5) done via LDS reads;
//                               at layer boundaries it fuses INTO the
//                               CNOT-Gray gather (4 reads + 8 coeff-FMA/amp)
// One LDS write + one barrier per layer. Gates on disjoint wires commute, so
// the order (0-3, 6-11, then 4-5) is exact.
// LDS layout f(i) = 18*(i>>4) + (i&15) (v2f units): every access is one base
// VGPR + compile-time immediates, 4-way conflicts max (b64 structural min).
// Final CNOT perm folds into measurement weights via inverse-Gray.

namespace {

typedef float v2f __attribute__((ext_vector_type(2)));

constexpr int DIM  = 4096;
constexpr int NG   = 36;
constexpr int PADA = 4606;       // max f = 288*15 + 18*15 + 15 = 4605

// ---- packed complex helpers (R6-verified). v2f = (re, im).
__device__ __forceinline__ v2f cmul(v2f u, v2f p) {
    v2f d;
    asm("v_pk_mul_f32 %0, %1, %2 op_sel_hi:[1,0]"
        : "=v"(d) : "v"(p), "v"(u));
    asm("v_pk_fma_f32 %0, %1, %2, %0 op_sel:[1,1,0] op_sel_hi:[0,1,1] neg_lo:[0,1,0]"
        : "+v"(d) : "v"(p), "v"(u));
    return d;
}
__device__ __forceinline__ void cfma(v2f& d, v2f u, v2f p) {
    asm("v_pk_fma_f32 %0, %1, %2, %0 op_sel_hi:[1,0,1]"
        : "+v"(d) : "v"(p), "v"(u));
    asm("v_pk_fma_f32 %0, %1, %2, %0 op_sel:[1,1,0] op_sel_hi:[0,1,1] neg_lo:[0,1,0]"
        : "+v"(d) : "v"(p), "v"(u));
}

// 4 in-register gates on k bits 3..0 (gate gg pairs k-bit 3-gg) = wires 0-3.
__device__ __forceinline__ void gates4(v2f amp[16], const v2f (*Um)[4], int gb)
{
    #pragma unroll
    for (int gg = 0; gg < 4; ++gg) {
        const v2f u00 = Um[gb + gg][0];
        const v2f u01 = Um[gb + gg][1];
        const v2f u10 = Um[gb + gg][2];
        const v2f u11 = Um[gb + gg][3];
        const int st = 8 >> gg;
        #pragma unroll
        for (int k0 = 0; k0 < 16; ++k0) {
            if (k0 & st) continue;             // static under full unroll
            const int k1 = k0 | st;
            const v2f p = amp[k0], q = amp[k1];
            v2f np = cmul(u00, p); cfma(np, u01, q);
            v2f nq = cmul(u10, p); cfma(nq, u11, q);
            amp[k0] = np;
            amp[k1] = nq;
        }
    }
}

__global__ __launch_bounds__(256, 2)
void qcirc_kernel(const float* __restrict__ state,
                  const float* __restrict__ weights,
                  const float* __restrict__ head_w,
                  const float* __restrict__ head_b,
                  float* __restrict__ out)
{
    __shared__ __align__(16) v2f buf[2][PADA];   // 73.7 KB total
    __shared__ __align__(16) v2f Um[NG][4];
    __shared__ float redbuf[4];

    const int t = threadIdx.x;                   // 8 bits
    const int b = blockIdx.x;

    // ---- 36 gate matrices. U = RZ(c)RY(b)RX(a); SU(2):
    // U = [[u00, -conj(u10)], [u10, conj(u00)]].
    if (t < NG) {
        const float* wp = weights + t * 3;
        float ha = 0.5f * wp[0], hb = 0.5f * wp[1], hc = 0.5f * wp[2];
        float ca = cosf(ha), sa = sinf(ha);
        float cb = cosf(hb), sb = sinf(hb);
        float ecr = cosf(hc), eci = -sinf(hc);   // e^{-i c/2}
        float t0 = cb * ca, t1 = sb * sa, t2 = sb * ca, t3 = cb * sa;
        float u00r =  ecr * t0 - eci * t1;
        float u00i =  ecr * t1 + eci * t0;
        float u10r =  ecr * t2 - eci * t3;
        float u10i = -ecr * t3 - eci * t2;
        Um[t][0] = (v2f){ u00r,  u00i};          // u00
        Um[t][1] = (v2f){-u10r,  u10i};          // u01 = -conj(u10)
        Um[t][2] = (v2f){ u10r,  u10i};          // u10
        Um[t][3] = (v2f){ u00r, -u00i};          // u11 = conj(u00)
    }

    // ---- bases (A-layout f(i)=18*(i>>4)+(i&15); i=(k<<8)|t => +288k).
    const int bA    = 18 * (t >> 4) + (t & 15);
    const int bA64  = 18 * ((t >> 4) ^ 4)  + (t & 15);   // partner t^64
    const int bA128 = 18 * ((t >> 4) ^ 8)  + (t & 15);   // partner t^128
    const int bA192 = 18 * ((t >> 4) ^ 12) + (t & 15);   // partner t^192
    // fused gather base: j = gray12((k<<8)|t) with bits 7,6 replaced;
    // addr = 288*gray4(k) + 144*b7' + 72*b6' + 18*gh2 + gl
    const int gt8 = (t ^ (t >> 1)) & 255;
    const int pbase = 18 * ((gt8 >> 4) & 3) + (gt8 & 15);
    const int t7 = (t >> 7) & 1, t6 = (t >> 6) & 1;
    const int j6 = t6 ^ t7;                      // thread-uniform j bit 6

    // ---- initial load (coalesced per k).
    v2f amp[16];
    {
        const float* sp = state + (size_t)b * DIM;
        #pragma unroll
        for (int k = 0; k < 16; ++k)
            amp[k] = (v2f){sp[(k << 8) | t], 0.f};
    }
    __syncthreads();                             // barrier 1: Um ready

    #pragma unroll 1
    for (int l = 0; l < 3; ++l) {
        const int gb = l * 12;
        if (l > 0) {
            // FUSED: previous layer's wave-gate (wires 4,5 = U4 x U5) +
            // CNOT-Gray perm, as a 4-slot gather. Even/odd k differ in j7.
            const v2f* src = buf[(l - 1) & 1];
            const v2f* U4 = Um[gb - 8];          // (l-1)*12 + 4
            const v2f* U5 = Um[gb - 7];
            const v2f a0  = t7 ? U4[2] : U4[0],  a1  = t7 ? U4[3] : U4[1];
            const v2f a0p = t7 ? U4[0] : U4[2],  a1p = t7 ? U4[1] : U4[3];
            const v2f b0  = j6 ? U5[2] : U5[0],  b1  = j6 ? U5[3] : U5[1];
            const v2f cE00 = cmul(a0,  b0), cE01 = cmul(a0,  b1);
            const v2f cE10 = cmul(a1,  b0), cE11 = cmul(a1,  b1);
            const v2f cO00 = cmul(a0p, b0), cO01 = cmul(a0p, b1);
            const v2f cO10 = cmul(a1p, b0), cO11 = cmul(a1p, b1);
            #pragma unroll
            for (int k = 0; k < 16; ++k) {
                const int g4 = k ^ (k >> 1);     // static
                const v2f* s = src + pbase + 288 * g4;
                const v2f r00 = s[0], r01 = s[72], r10 = s[144], r11 = s[216];
                v2f nw;
                if (k & 1) {
                    nw = cmul(cO00, r00); cfma(nw, cO01, r01);
                    cfma(nw, cO10, r10);  cfma(nw, cO11, r11);
                } else {
                    nw = cmul(cE00, r00); cfma(nw, cE01, r01);
                    cfma(nw, cE10, r10);  cfma(nw, cE11, r11);
                }
                amp[k] = nw;
            }
        }

        // wires 0-3: in-register
        gates4(amp, Um, gb);

        // wires 6-11: shuffle gates on lane bits 5..0 (no barrier)
        #pragma unroll
        for (int w6 = 0; w6 < 6; ++w6) {
            const v2f* Ug = Um[gb + 6 + w6];
            const v2f u00 = Ug[0], u01 = Ug[1], u10 = Ug[2], u11 = Ug[3];
            const int mask = 32 >> w6;
            const bool bo = (t & mask) != 0;
            const v2f uA = bo ? u11 : u00;       // own-coefficient
            const v2f uB = bo ? u10 : u01;       // partner-coefficient
            #pragma unroll
            for (int k = 0; k < 16; ++k) {
                v2f oth;
                oth.x = __shfl_xor(amp[k].x, mask, 64);
                oth.y = __shfl_xor(amp[k].y, mask, 64);
                v2f nw = cmul(uA, amp[k]);
                cfma(nw, uB, oth);
                amp[k] = nw;
            }
        }

        // write A-layout (pre-wave-gate state of this layer)
        {
            v2f* dst = buf[l & 1];
            #pragma unroll
            for (int k = 0; k < 16; ++k) dst[bA + 288 * k] = amp[k];
        }
        __syncthreads();                         // barriers 2-4
    }

    // ---- layer-2 wave-gate (wires 4,5), direct: 3 partner reads from buf0.
    {
        const v2f* src = buf[0];
        const v2f* U4 = Um[28];
        const v2f* U5 = Um[29];
        const v2f a_own = t7 ? U4[3] : U4[0];    // U4[t7][t7]
        const v2f a_oth = t7 ? U4[2] : U4[1];    // U4[t7][t7^1]
        const v2f b_own = t6 ? U5[3] : U5[0];
        const v2f b_oth = t6 ? U5[2] : U5[1];
        const v2f c_own = cmul(a_own, b_own);
        const v2f c_64  = cmul(a_own, b_oth);
        const v2f c_128 = cmul(a_oth, b_own);
        const v2f c_192 = cmul(a_oth, b_oth);
        #pragma unroll
        for (int k = 0; k < 16; ++k) {
            const int base = 288 * k;
            const v2f r64  = src[bA64  + base];
            const v2f r128 = src[bA128 + base];
            const v2f r192 = src[bA192 + base];
            v2f nw = cmul(c_own, amp[k]);
            cfma(nw, c_64,  r64);
            cfma(nw, c_128, r128);
            cfma(nw, c_192, r192);
            amp[k] = nw;
        }
    }

    // ---- measurement. Regs hold final pre-perm state at i=(k<<8)|t;
    // logical m = invGray12(i): m[11:8]=invGray4(k),
    // m[7:0]=invGray8(t)^(par4(k)*0xFF).
    // acc = sum_w=0..3 hw[w]*S_w + chi(t) * Sp,
    //   S_w sign from invGray4(k) bit (3-w) [static], Sp sign = (-1)^par(k),
    //   chi(t) = sum_w=4..11 hw[w]*(1-2*invGray8(t)[11-w]).
    float hw[12];
    #pragma unroll
    for (int w = 0; w < 12; ++w) hw[w] = head_w[w];

    float S0 = 0.f, S1 = 0.f, S2 = 0.f, S3 = 0.f, Sp = 0.f;
    #pragma unroll
    for (int k = 0; k < 16; ++k) {
        const float p = amp[k].x * amp[k].x + amp[k].y * amp[k].y;
        const int ig4 = (k ^ (k >> 1) ^ (k >> 2) ^ (k >> 3)) & 15;  // static
        S0 += (ig4 & 8) ? -p : p;
        S1 += (ig4 & 4) ? -p : p;
        S2 += (ig4 & 2) ? -p : p;
        S3 += (ig4 & 1) ? -p : p;
        Sp += (__popc(k) & 1) ? -p : p;
    }
    int ig8 = t ^ (t >> 1); ig8 ^= ig8 >> 2; ig8 ^= ig8 >> 4; ig8 &= 255;
    float chi = 0.f;
    #pragma unroll
    for (int w = 4; w < 12; ++w)
        chi += ((ig8 >> (11 - w)) & 1) ? -hw[w] : hw[w];

    float acc = hw[0] * S0 + hw[1] * S1 + hw[2] * S2 + hw[3] * S3 + chi * Sp;

    #pragma unroll
    for (int off = 32; off > 0; off >>= 1)
        acc += __shfl_down(acc, off, 64);
    if ((t & 63) == 0) redbuf[t >> 6] = acc;
    __syncthreads();                             // barrier 5
    if (t == 0)
        out[b] = redbuf[0] + redbuf[1] + redbuf[2] + redbuf[3] + head_b[0];
}

} // namespace

extern "C" void kernel_launch(void* const* d_in, const int* in_sizes, int n_in,
                              void* d_out, int out_size, void* d_ws, size_t ws_size,
                              hipStream_t stream)
{
    const float* state   = (const float*)d_in[0];  // (B, 4096) fp32
    const float* weights = (const float*)d_in[1];  // (3, 12, 3) fp32
    const float* head_w  = (const float*)d_in[2];  // (1, 12) fp32
    const float* head_b  = (const float*)d_in[3];  // (1,) fp32
    float* out = (float*)d_out;                    // (B,) fp32

    const int batch = in_sizes[0] / DIM;           // 512
    qcirc_kernel<<<batch, 256, 0, stream>>>(state, weights, head_w, head_b, out);
}